// Round 1
// baseline (194.039 us; speedup 1.0000x reference)
//
#include <hip/hip_runtime.h>
#include <stdint.h>

// HashEncoder: L=16 levels, T=16384 hash-table entries, F=2 features, 3-D input.
// Thread = (point n, level l), l in low 4 bits so the float2 output store at
// out[tid] is perfectly coalesced (n*32 + l*2 floats == tid*2 floats).
constexpr int L_LEVELS = 16;
constexpr int T_SIZE   = 16384;
constexpr int N_PTS    = 262144;

__global__ __launch_bounds__(256) void hash_encode_kernel(
    const float* __restrict__ x,
    const float* __restrict__ emb,
    float2* __restrict__ out)
{
    int tid = blockIdx.x * blockDim.x + threadIdx.x;   // tid = n*16 + l
    int l = tid & (L_LEVELS - 1);
    int n = tid >> 4;

    // N_l = 16 * (32)^(l/16) = 16 * 2^(5l/16); 0.3125f = 5/16 exact, l*0.3125f exact.
    float Nl = 16.0f * exp2f((float)l * 0.3125f);

    float xv0 = x[n * 3 + 0];
    float xv1 = x[n * 3 + 1];
    float xv2 = x[n * 3 + 2];

    float u0 = xv0 * Nl, u1 = xv1 * Nl, u2 = xv2 * Nl;
    float fl0 = floorf(u0), fl1 = floorf(u1), fl2 = floorf(u2);
    float ce0 = ceilf(u0),  ce1 = ceilf(u1),  ce2 = ceilf(u2);
    // d = ce - fl is 1 (generic) or 0 (u exactly integer); diff=0 in the 0 case.
    float df0 = (ce0 != fl0) ? (u0 - fl0) : 0.0f;
    float df1 = (ce1 != fl1) ? (u1 - fl1) : 0.0f;
    float df2 = (ce2 != fl2) ? (u2 - fl2) : 0.0f;

    // Hash products per dim for lo and hi corner coords (wrapping int32 == uint32 mul).
    uint32_t p0l = (uint32_t)(int32_t)fl0;                       // prime 1
    uint32_t p0h = (uint32_t)(int32_t)ce0;
    uint32_t p1l = (uint32_t)(int32_t)fl1 * 2654435761u;
    uint32_t p1h = (uint32_t)(int32_t)ce1 * 2654435761u;
    uint32_t p2l = (uint32_t)(int32_t)fl2 * 805459861u;
    uint32_t p2h = (uint32_t)(int32_t)ce2 * 805459861u;

    const float2* __restrict__ tab =
        reinterpret_cast<const float2*>(emb) + l * T_SIZE;

    // Issue all 8 gathers first (independent loads -> latency overlap).
    float2 f[8];
#pragma unroll
    for (int k = 0; k < 8; ++k) {
        uint32_t h = ((k & 4) ? p0h : p0l)
                   ^ ((k & 2) ? p1h : p1l)
                   ^ ((k & 1) ? p2h : p2l);
        // jnp.mod(int32, 16384) == two's-complement bitwise AND with 16383.
        f[k] = tab[h & (T_SIZE - 1)];
    }

    float acc0 = 0.0f, acc1 = 0.0f;
#pragma unroll
    for (int k = 0; k < 8; ++k) {
        float w = ((k & 4) ? df0 : 1.0f - df0)
                * ((k & 2) ? df1 : 1.0f - df1)
                * ((k & 1) ? df2 : 1.0f - df2);
        acc0 += w * f[k].x;
        acc1 += w * f[k].y;
    }

    out[tid] = make_float2(acc0, acc1);
}

extern "C" void kernel_launch(void* const* d_in, const int* in_sizes, int n_in,
                              void* d_out, int out_size, void* d_ws, size_t ws_size,
                              hipStream_t stream) {
    const float* x   = (const float*)d_in[0];
    const float* emb = (const float*)d_in[1];
    float2* out      = (float2*)d_out;

    int total  = N_PTS * L_LEVELS;           // 4,194,304 threads, exact multiple of 256
    int blocks = total / 256;
    hash_encode_kernel<<<blocks, 256, 0, stream>>>(x, emb, out);
}

// Round 2
// 92.734 us; speedup vs baseline: 2.0924x; 2.0924x over previous
//
#include <hip/hip_runtime.h>
#include <stdint.h>

constexpr int L_LEVELS = 16;
constexpr int T_SIZE   = 16384;
constexpr int N_PTS    = 262144;

// ---------------------------------------------------------------------------
// Kernel A: one block = (level, chunk of 16384 points). Stage the level's
// 128 KB table into LDS, serve all 8 corner gathers from LDS.
// DIRECT=false: write level-major ws[l*N + n]   (coalesced; transpose later)
// DIRECT=true : write out[(n*16 + l)]           (strided fallback, no ws)
// ---------------------------------------------------------------------------
template <bool DIRECT>
__global__ __launch_bounds__(1024, 1) void hash_encode_lds(
    const float* __restrict__ x,
    const float* __restrict__ emb,
    float2* __restrict__ dst)
{
    __shared__ __align__(16) float2 tab[T_SIZE];   // 128 KB (gfx950 LDS = 160 KB)

    const int l     = blockIdx.x & (L_LEVELS - 1);       // level in low bits
    const int chunk = blockIdx.x >> 4;                   // 16 chunks per level
    const int t     = threadIdx.x;                       // 0..1023
    const int base  = chunk * 16384;

    // ---- stage table: 131072 B as 8192 float4, 8 per thread, coalesced ----
    {
        const float4* __restrict__ src =
            reinterpret_cast<const float4*>(emb + (size_t)l * T_SIZE * 2);
        float4* __restrict__ d4 = reinterpret_cast<float4*>(tab);
#pragma unroll
        for (int it = 0; it < 8; ++it)
            d4[it * 1024 + t] = src[it * 1024 + t];
    }
    __syncthreads();

    // N_l = 16 * 2^(5l/16); l*0.3125f exact.
    const float Nl = 16.0f * exp2f((float)l * 0.3125f);

#pragma unroll 4
    for (int p = 0; p < 16; ++p) {
        const int n = base + p * 1024 + t;

        const float u0 = x[n * 3 + 0] * Nl;
        const float u1 = x[n * 3 + 1] * Nl;
        const float u2 = x[n * 3 + 2] * Nl;

        const float fl0 = floorf(u0), fl1 = floorf(u1), fl2 = floorf(u2);
        const float ce0 = ceilf(u0),  ce1 = ceilf(u1),  ce2 = ceilf(u2);
        const float df0 = (ce0 != fl0) ? (u0 - fl0) : 0.0f;
        const float df1 = (ce1 != fl1) ? (u1 - fl1) : 0.0f;
        const float df2 = (ce2 != fl2) ? (u2 - fl2) : 0.0f;

        const uint32_t p0l = (uint32_t)(int32_t)fl0;
        const uint32_t p0h = (uint32_t)(int32_t)ce0;
        const uint32_t p1l = (uint32_t)(int32_t)fl1 * 2654435761u;
        const uint32_t p1h = (uint32_t)(int32_t)ce1 * 2654435761u;
        const uint32_t p2l = (uint32_t)(int32_t)fl2 * 805459861u;
        const uint32_t p2h = (uint32_t)(int32_t)ce2 * 805459861u;

        float2 f[8];
#pragma unroll
        for (int k = 0; k < 8; ++k) {
            uint32_t h = ((k & 4) ? p0h : p0l)
                       ^ ((k & 2) ? p1h : p1l)
                       ^ ((k & 1) ? p2h : p2l);
            f[k] = tab[h & (T_SIZE - 1)];
        }

        float acc0 = 0.0f, acc1 = 0.0f;
#pragma unroll
        for (int k = 0; k < 8; ++k) {
            const float w = ((k & 4) ? df0 : 1.0f - df0)
                          * ((k & 2) ? df1 : 1.0f - df1)
                          * ((k & 1) ? df2 : 1.0f - df2);
            acc0 += w * f[k].x;
            acc1 += w * f[k].y;
        }

        if (DIRECT)
            dst[(size_t)n * L_LEVELS + l] = make_float2(acc0, acc1);   // strided
        else
            dst[(size_t)l * N_PTS + n]   = make_float2(acc0, acc1);   // coalesced
    }
}

// ---------------------------------------------------------------------------
// Kernel B: transpose ws (L, N, f2) -> out (N, L, f2) via LDS tile.
// Block = 256 threads, tile = 256 points x 16 levels. Row stride 257 f2
// makes the write-phase LDS reads (16 lanes sharing p, distinct l) hit
// 16 distinct bank pairs.
// ---------------------------------------------------------------------------
__global__ __launch_bounds__(256) void transpose_lnf_nlf(
    const float2* __restrict__ ws,
    float2* __restrict__ out)
{
    __shared__ float2 tile[L_LEVELS][257];
    const int t    = threadIdx.x;
    const int base = blockIdx.x * 256;

#pragma unroll
    for (int l = 0; l < L_LEVELS; ++l)
        tile[l][t] = ws[(size_t)l * N_PTS + base + t];   // coalesced 8 B/lane
    __syncthreads();

#pragma unroll
    for (int i = 0; i < L_LEVELS; ++i) {
        const int flat = i * 256 + t;                    // p*16 + l
        const int p = flat >> 4;
        const int l = flat & 15;
        out[(size_t)base * L_LEVELS + flat] = tile[l][p]; // coalesced 8 B/lane
    }
}

extern "C" void kernel_launch(void* const* d_in, const int* in_sizes, int n_in,
                              void* d_out, int out_size, void* d_ws, size_t ws_size,
                              hipStream_t stream) {
    const float* x   = (const float*)d_in[0];
    const float* emb = (const float*)d_in[1];
    float2* out      = (float2*)d_out;

    const size_t ws_needed = (size_t)N_PTS * L_LEVELS * sizeof(float2); // 32 MiB

    if (ws_size >= ws_needed) {
        float2* ws = (float2*)d_ws;
        hash_encode_lds<false><<<256, 1024, 0, stream>>>(x, emb, ws);
        transpose_lnf_nlf<<<N_PTS / 256, 256, 0, stream>>>(ws, out);
    } else {
        hash_encode_lds<true><<<256, 1024, 0, stream>>>(x, emb, out);
    }
}

// Round 3
// 87.556 us; speedup vs baseline: 2.2162x; 1.0591x over previous
//
#include <hip/hip_runtime.h>
#include <stdint.h>

constexpr int L_LEVELS = 16;
constexpr int T_SIZE   = 16384;
constexpr int N_PTS    = 262144;

typedef _Float16 h2 __attribute__((ext_vector_type(2)));
typedef _Float16 h4 __attribute__((ext_vector_type(4)));

// ---------------------------------------------------------------------------
// Kernel A: block = (level, chunk of 8192 points), 1024 threads.
// Level table staged into LDS as half2 (64 KB -> 2 blocks/CU, 32 waves).
// Gathers are random ds_read_b32 (half the LDS cycles of the float2 b64).
// DIRECT=false: ws[l*N + n] as half2 (coalesced 4 B/lane; transpose later)
// DIRECT=true : out[n*16 + l] as float2 (strided fallback, no ws)
// ---------------------------------------------------------------------------
template <bool DIRECT>
__global__ __launch_bounds__(1024, 8) void hash_encode_lds(
    const float* __restrict__ x,
    const float* __restrict__ emb,
    void* __restrict__ dst_raw)
{
    __shared__ __align__(16) h2 tab[T_SIZE];             // 64 KB

    const int l     = blockIdx.x & (L_LEVELS - 1);
    const int chunk = blockIdx.x >> 4;                   // 0..31
    const int t     = threadIdx.x;                       // 0..1023
    const int base  = chunk * 8192;

    // ---- stage table: 16384 f2 entries -> half2, via float4 (2 entries) ----
    {
        const float4* __restrict__ src =
            reinterpret_cast<const float4*>(emb + (size_t)l * T_SIZE * 2);
        h4* __restrict__ d4 = reinterpret_cast<h4*>(tab);
#pragma unroll
        for (int it = 0; it < 8; ++it) {
            const int i = it * 1024 + t;                 // < 8192
            float4 v = src[i];                           // entries 2i, 2i+1
            h4 w = { (_Float16)v.x, (_Float16)v.y,       // RN converts
                     (_Float16)v.z, (_Float16)v.w };
            d4[i] = w;                                   // 8 B/lane, conflict-free
        }
    }
    __syncthreads();

    // N_l = 16 * 2^(5l/16); l*0.3125f exact.
    const float Nl = 16.0f * exp2f((float)l * 0.3125f);

#pragma unroll 2
    for (int p = 0; p < 8; ++p) {
        const int n = base + p * 1024 + t;

        const float u0 = x[n * 3 + 0] * Nl;
        const float u1 = x[n * 3 + 1] * Nl;
        const float u2 = x[n * 3 + 2] * Nl;

        const float fl0 = floorf(u0), fl1 = floorf(u1), fl2 = floorf(u2);
        const float ce0 = ceilf(u0),  ce1 = ceilf(u1),  ce2 = ceilf(u2);
        const float df0 = (ce0 != fl0) ? (u0 - fl0) : 0.0f;
        const float df1 = (ce1 != fl1) ? (u1 - fl1) : 0.0f;
        const float df2 = (ce2 != fl2) ? (u2 - fl2) : 0.0f;

        const uint32_t p0l = (uint32_t)(int32_t)fl0;     // prime 1
        const uint32_t p0h = (uint32_t)(int32_t)ce0;
        const uint32_t p1l = (uint32_t)(int32_t)fl1 * 2654435761u;
        const uint32_t p1h = (uint32_t)(int32_t)ce1 * 2654435761u;
        const uint32_t p2l = (uint32_t)(int32_t)fl2 * 805459861u;
        const uint32_t p2h = (uint32_t)(int32_t)ce2 * 805459861u;

        h2 f[8];
#pragma unroll
        for (int k = 0; k < 8; ++k) {
            uint32_t h = ((k & 4) ? p0h : p0l)
                       ^ ((k & 2) ? p1h : p1l)
                       ^ ((k & 1) ? p2h : p2l);
            f[k] = tab[h & (T_SIZE - 1)];                // random ds_read_b32
        }

        float acc0 = 0.0f, acc1 = 0.0f;
#pragma unroll
        for (int k = 0; k < 8; ++k) {
            const float w = ((k & 4) ? df0 : 1.0f - df0)
                          * ((k & 2) ? df1 : 1.0f - df1)
                          * ((k & 1) ? df2 : 1.0f - df2);
            acc0 += w * (float)f[k].x;
            acc1 += w * (float)f[k].y;
        }

        if (DIRECT) {
            float2* out = reinterpret_cast<float2*>(dst_raw);
            out[(size_t)n * L_LEVELS + l] = make_float2(acc0, acc1);
        } else {
            h2* ws = reinterpret_cast<h2*>(dst_raw);
            h2 r = { (_Float16)acc0, (_Float16)acc1 };
            ws[(size_t)l * N_PTS + n] = r;               // coalesced 4 B/lane
        }
    }
}

// ---------------------------------------------------------------------------
// Kernel B: transpose ws (L, N) half2 -> out (N, L) float2 via LDS tile.
// Block = 256 threads, tile = 256 points x 16 levels, row stride 257.
// ---------------------------------------------------------------------------
__global__ __launch_bounds__(256) void transpose_lnf_nlf(
    const h2* __restrict__ ws,
    float2* __restrict__ out)
{
    __shared__ h2 tile[L_LEVELS][257];
    const int t    = threadIdx.x;
    const int base = blockIdx.x * 256;

#pragma unroll
    for (int l = 0; l < L_LEVELS; ++l)
        tile[l][t] = ws[(size_t)l * N_PTS + base + t];   // coalesced 4 B/lane
    __syncthreads();

#pragma unroll
    for (int i = 0; i < L_LEVELS; ++i) {
        const int flat = i * 256 + t;                    // p*16 + l
        const int p = flat >> 4;
        const int l = flat & 15;
        h2 v = tile[l][p];
        out[(size_t)base * L_LEVELS + flat] =
            make_float2((float)v.x, (float)v.y);         // coalesced 8 B/lane
    }
}

extern "C" void kernel_launch(void* const* d_in, const int* in_sizes, int n_in,
                              void* d_out, int out_size, void* d_ws, size_t ws_size,
                              hipStream_t stream) {
    const float* x   = (const float*)d_in[0];
    const float* emb = (const float*)d_in[1];

    const size_t ws_needed = (size_t)N_PTS * L_LEVELS * sizeof(h2); // 16 MiB

    if (ws_size >= ws_needed) {
        hash_encode_lds<false><<<512, 1024, 0, stream>>>(x, emb, d_ws);
        transpose_lnf_nlf<<<N_PTS / 256, 256, 0, stream>>>((const h2*)d_ws,
                                                           (float2*)d_out);
    } else {
        hash_encode_lds<true><<<512, 1024, 0, stream>>>(x, emb, d_out);
    }
}